// Round 12
// baseline (390.587 us; speedup 1.0000x reference)
//
#include <hip/hip_runtime.h>
#include <hip/hip_bf16.h>

// Problem constants
constexpr int BB = 2;
constexpr int SS = 2048;
constexpr int EE = 1024;
constexpr int HH = 16;
constexpr int DD = 64;
constexpr int MM = BB * SS;              // 4096 rows in the projection GEMMs
constexpr int CX = MM * EE;              // 4194304 elems per X slice (2^22)
constexpr int CW = EE * EE;              // 1048576 elems per W slice (2^20)
// Q pre-scale: 1/sqrt(EMBED_DIM) * log2(e) so attention scores are base-2 logits
#define QSCALE 0.045084220027780106f
#define NEGBIG -1e30f

typedef __attribute__((ext_vector_type(8))) short short8;    // 8 bf16 = 4 VGPRs (MFMA A/B frag)
typedef __attribute__((ext_vector_type(4))) float floatx4;   // MFMA C/D frag

__device__ inline short bf16bits(float x) {
    __hip_bfloat16 h = __float2bfloat16(x);
    return *reinterpret_cast<short*>(&h);
}

__device__ inline unsigned pkbf(float a, float b) {
    return (unsigned)(unsigned short)bf16bits(a) |
           ((unsigned)(unsigned short)bf16bits(b) << 16);
}

__device__ inline float fast_exp2(float x) {
#if __has_builtin(__builtin_amdgcn_exp2f)
    return __builtin_amdgcn_exp2f(x);
#else
    return exp2f(x);
#endif
}

// Async global->LDS, 16 B per lane. LDS dest = wave-uniform base + lane*16.
__device__ inline void gl_lds16(const __hip_bfloat16* g, const short* l) {
    __builtin_amdgcn_global_load_lds(
        (const __attribute__((address_space(1))) void*)g,
        (__attribute__((address_space(3))) void*)l, 16, 0, 0);
}

__device__ inline short8 ldg8bf(const __hip_bfloat16* p) {
    return *reinterpret_cast<const short8*>(p);
}

// ---------------------------------------------------------------------------
// Convert pass: f32 -> bf16, flat over 3 X slices then 3 W slices.
// ---------------------------------------------------------------------------
__global__ __launch_bounds__(256) void convert_kernel(
    const float* __restrict__ x0, const float* __restrict__ x1, const float* __restrict__ x2,
    const float* __restrict__ w0, const float* __restrict__ w1, const float* __restrict__ w2,
    __hip_bfloat16* __restrict__ xb, __hip_bfloat16* __restrict__ wb)
{
    const long long e = (long long)(blockIdx.x * 256 + threadIdx.x) * 8;
    const float* src;
    __hip_bfloat16* dst;
    if (e < 3LL * CX) {
        const int z = (int)(e >> 22);
        const int off = (int)(e & (CX - 1));
        src = ((z == 0) ? x0 : (z == 1) ? x1 : x2) + off;
        dst = xb + e;
    } else {
        const long long e2 = e - 3LL * CX;
        const int z = (int)(e2 >> 20);
        const int off = (int)(e2 & (CW - 1));
        src = ((z == 0) ? w0 : (z == 1) ? w1 : w2) + off;
        dst = wb + e2;
    }
    const float4 a = reinterpret_cast<const float4*>(src)[0];
    const float4 b = reinterpret_cast<const float4*>(src)[1];
    short8 r;
    r[0] = bf16bits(a.x); r[1] = bf16bits(a.y); r[2] = bf16bits(a.z); r[3] = bf16bits(a.w);
    r[4] = bf16bits(b.x); r[5] = bf16bits(b.y); r[6] = bf16bits(b.z); r[7] = bf16bits(b.w);
    *reinterpret_cast<short8*>(dst) = r;
}

// ---------------------------------------------------------------------------
// Projection GEMM (r8 version — best measured): 128x128 tile, BK=32,
// 256 threads, 2-barrier K-loop, async global_load_lds, superrow swizzle
// (granule pos=(r&1)*4+g of row r at slot pos^((r>>1)&7) -> 2-way-free b128
// frag reads with the contiguous DMA dest global_load_lds requires).
// which==0 output (Q) pre-scaled by QSCALE. V stored transposed [B,H,D,S].
// ---------------------------------------------------------------------------
__global__ __launch_bounds__(256) void proj_gemm(
    const __hip_bfloat16* __restrict__ xb,
    const __hip_bfloat16* __restrict__ wb,
    const float* __restrict__ bq, const float* __restrict__ bk, const float* __restrict__ bv,
    __hip_bfloat16* __restrict__ qws,
    __hip_bfloat16* __restrict__ kws,
    __hip_bfloat16* __restrict__ vtws)
{
    const int which = blockIdx.z;
    const __hip_bfloat16* A = xb + (size_t)which * CX;
    const __hip_bfloat16* W = wb + (size_t)which * CW;
    const float* bias = (which == 0) ? bq : (which == 1) ? bk : bv;

    const int m0   = blockIdx.x * 128;
    const int n0   = blockIdx.y * 128;
    const int tid  = threadIdx.x;
    const int wave = tid >> 6;
    const int lane = tid & 63;
    const int l15  = lane & 15;
    const int quad = lane >> 4;
    const int wr   = wave >> 1;
    const int wc   = wave & 1;

    __shared__ __align__(16) short As[128 * 32];   // 8 KiB, superrow-swizzled
    __shared__ __align__(16) short Bs[128 * 32];   // 8 KiB

    const int dpos  = (lane & 7) ^ (lane >> 3);
    const int drloc = 2 * (lane >> 3) + (dpos >> 2);
    const int dgran = (dpos & 3) * 8;              // k-offset in shorts

    const int rbase = (l15 >> 1) * 64;             // superrow offset within tile
    const int rslot = (((l15 & 1) * 4 + quad) ^ (l15 >> 1)) * 8;

    floatx4 acc[4][4] = {};

    for (int k0 = 0; k0 < EE; k0 += 32) {
        __syncthreads();  // WAR: previous iteration's frag reads complete
        #pragma unroll
        for (int p = 0; p < 2; ++p) {
            const int rb16 = wave * 32 + p * 16;   // 16-row issue base
            gl_lds16(A + (size_t)(m0 + rb16 + drloc) * EE + k0 + dgran, &As[rb16 * 32]);
            gl_lds16(W + (size_t)(n0 + rb16 + drloc) * EE + k0 + dgran, &Bs[rb16 * 32]);
        }
        __syncthreads();  // staging visible (drains vmcnt)

        short8 af[4], bf[4];
        #pragma unroll
        for (int mt = 0; mt < 4; ++mt)
            af[mt] = *reinterpret_cast<const short8*>(
                &As[(wr * 32 + mt * 8) * 64 + rbase + rslot]);
        #pragma unroll
        for (int nt = 0; nt < 4; ++nt)
            bf[nt] = *reinterpret_cast<const short8*>(
                &Bs[(wc * 32 + nt * 8) * 64 + rbase + rslot]);

        #pragma unroll
        for (int mt = 0; mt < 4; ++mt)
            #pragma unroll
            for (int nt = 0; nt < 4; ++nt)
                acc[mt][nt] = __builtin_amdgcn_mfma_f32_16x16x32_bf16(af[mt], bf[nt], acc[mt][nt], 0, 0, 0);
    }

    // Epilogue: C/D layout col = lane&15, row = quad*4 + r
    #pragma unroll
    for (int nt = 0; nt < 4; ++nt) {
        const int n = n0 + wc * 64 + nt * 16 + l15;
        const float bval = bias[n];
        const int h = n >> 6, d = n & 63;
        #pragma unroll
        for (int mt = 0; mt < 4; ++mt) {
            #pragma unroll
            for (int r = 0; r < 4; ++r) {
                const int m = m0 + wr * 64 + mt * 16 + quad * 4 + r;
                const int b = m >> 11;
                const int s = m & (SS - 1);
                float val = acc[mt][nt][r] + bval;
                if (which == 0) val *= QSCALE;   // fold softmax scale+log2e into Q
                const __hip_bfloat16 hv = __float2bfloat16(val);
                if (which == 0)
                    qws[(((size_t)b * HH + h) * SS + s) * DD + d] = hv;
                else if (which == 1)
                    kws[(((size_t)b * HH + h) * SS + s) * DD + d] = hv;
                else
                    vtws[(((size_t)b * HH + h) * DD + d) * SS + s] = hv;
            }
        }
    }
}

// ---------------------------------------------------------------------------
// Flash attention, BARRIER-FREE. K and V fragments load directly from global
// (both 16 B/lane contiguous: K A-frags from kws[key][d], V B-frags from
// vtws[d][key]); the 4x intra-block redundancy hits L1 (16 KB tile working
// set < 32 KB L1), the rest L2/L3. LDS holds ONLY the per-wave P transpose
// (8 KB), needing just a wave-local lgkmcnt wait -> ZERO __syncthreads.
// Transposed-score + no-max softmax (scores bounded; masked keys -1e30 ->
// exp2 = 0 exactly). 64 q-rows per block, 4 waves.
// ---------------------------------------------------------------------------
__global__ __launch_bounds__(256) void attn_kernel(
    const __hip_bfloat16* __restrict__ qws,
    const __hip_bfloat16* __restrict__ kws,
    const __hip_bfloat16* __restrict__ vtws,
    const int* __restrict__ amask,
    float* __restrict__ out)
{
    const int bh   = blockIdx.y;
    const int b    = bh >> 4;
    const int q0   = blockIdx.x * 64;
    const int tid  = threadIdx.x;
    const int wave = tid >> 6;
    const int lane = tid & 63;
    const int l15  = lane & 15;
    const int quad = lane >> 4;

    const __hip_bfloat16* Q  = qws  + (size_t)bh * SS * DD;
    const __hip_bfloat16* K  = kws  + (size_t)bh * SS * DD;
    const __hip_bfloat16* VT = vtws + (size_t)bh * DD * SS;
    const int* msk = amask + b * SS;

    __shared__ __align__(16) short Ps[4][16 * 64];   // per-wave P[q][key], swizzled
    short* pw = Ps[wave];

    // Q fragment (B-operand of S^T): q = l15, k-granules quad / quad+4
    const int qrow = q0 + wave * 16 + l15;
    const short8 qa0 = ldg8bf(Q + (size_t)qrow * DD + quad * 8);
    const short8 qa1 = ldg8bf(Q + (size_t)qrow * DD + 32 + quad * 8);

    const int swz = l15 & 7;   // P swizzle key

    float l_lane = 0.f;      // per-lane partial sum-of-P (q = l15)
    floatx4 acc[4] = {};     // O: col = d (l15), row = q (quad*4+r)

    for (int kt = 0; kt < SS; kt += 64) {
        // --- S^T: st[f] holds keys f*16+quad*4+r (rows), q = l15 (cols).
        //     K A-frags straight from global: K[key=f*16+l15][k=quad*8+j] ---
        floatx4 st[4];
        #pragma unroll
        for (int f = 0; f < 4; ++f) {
            const __hip_bfloat16* kp = K + (size_t)(kt + f * 16 + l15) * DD + quad * 8;
            floatx4 z = {};
            z = __builtin_amdgcn_mfma_f32_16x16x32_bf16(ldg8bf(kp),      qa0, z, 0, 0, 0);
            z = __builtin_amdgcn_mfma_f32_16x16x32_bf16(ldg8bf(kp + 32), qa1, z, 0, 0, 0);
            st[f] = z;
        }

        // --- P = exp2(score + maskbias); accumulate l in-lane ---
        #pragma unroll
        for (int f = 0; f < 4; ++f) {
            const int4 mi = *reinterpret_cast<const int4*>(msk + kt + f * 16 + quad * 4);
            st[f][0] = fast_exp2(st[f][0] + (mi.x ? 0.f : NEGBIG));
            st[f][1] = fast_exp2(st[f][1] + (mi.y ? 0.f : NEGBIG));
            st[f][2] = fast_exp2(st[f][2] + (mi.z ? 0.f : NEGBIG));
            st[f][3] = fast_exp2(st[f][3] + (mi.w ? 0.f : NEGBIG));
            l_lane += st[f][0] + st[f][1] + st[f][2] + st[f][3];
        }

        // --- store P[q=l15][key] as uint2 into swizzled slots (per-wave) ---
        #pragma unroll
        for (int f = 0; f < 4; ++f) {
            const int slot = (2 * f + (quad >> 1)) ^ swz;
            uint2 pk;
            pk.x = pkbf(st[f][0], st[f][1]);
            pk.y = pkbf(st[f][2], st[f][3]);
            *reinterpret_cast<uint2*>(pw + l15 * 64 + slot * 8 + (quad & 1) * 4) = pk;
        }
        __asm__ volatile("s_waitcnt lgkmcnt(0)" ::: "memory");  // wave-local P drain

        const short8 pa0 = *reinterpret_cast<const short8*>(pw + l15 * 64 + (quad ^ swz) * 8);
        const short8 pa1 = *reinterpret_cast<const short8*>(pw + l15 * 64 + ((quad + 4) ^ swz) * 8);

        // --- PV: V B-frags straight from global (VT contiguous along key) ---
        #pragma unroll
        for (int nt = 0; nt < 4; ++nt) {
            const __hip_bfloat16* vp = VT + (size_t)(nt * 16 + l15) * SS + kt + quad * 8;
            acc[nt] = __builtin_amdgcn_mfma_f32_16x16x32_bf16(pa0, ldg8bf(vp),      acc[nt], 0, 0, 0);
            acc[nt] = __builtin_amdgcn_mfma_f32_16x16x32_bf16(pa1, ldg8bf(vp + 32), acc[nt], 0, 0, 0);
        }
    }

    // --- epilogue: one cross-quad l reduction, then broadcast per q-row ---
    l_lane += __shfl_xor(l_lane, 16, 64);
    l_lane += __shfl_xor(l_lane, 32, 64);
    float lq[4];
    #pragma unroll
    for (int r = 0; r < 4; ++r)
        lq[r] = __shfl(l_lane, quad * 4 + r, 16);

    const size_t obase = (size_t)bh * SS * DD;
    #pragma unroll
    for (int nt = 0; nt < 4; ++nt)
        #pragma unroll
        for (int r = 0; r < 4; ++r) {
            const int qq = q0 + wave * 16 + quad * 4 + r;
            const int d  = nt * 16 + l15;
            out[obase + (size_t)qq * DD + d] = acc[nt][r] / lq[r];
        }
}

extern "C" void kernel_launch(void* const* d_in, const int* in_sizes, int n_in,
                              void* d_out, int out_size, void* d_ws, size_t ws_size,
                              hipStream_t stream) {
    const float* q    = (const float*)d_in[0];
    const float* k    = (const float*)d_in[1];
    const float* v    = (const float*)d_in[2];
    const int*   mask = (const int*)d_in[3];
    const float* Wq   = (const float*)d_in[4];
    const float* bq   = (const float*)d_in[5];
    const float* Wk   = (const float*)d_in[6];
    const float* bk   = (const float*)d_in[7];
    const float* Wv   = (const float*)d_in[8];
    const float* bv   = (const float*)d_in[9];
    float* out = (float*)d_out;

    // Workspace (shorts): qws | kws | vtws | Xbf(3) | Wbf(3)
    __hip_bfloat16* qws  = (__hip_bfloat16*)d_ws;
    __hip_bfloat16* kws  = qws + (size_t)CX;
    __hip_bfloat16* vtws = kws + (size_t)CX;
    __hip_bfloat16* xb   = vtws + (size_t)CX;
    __hip_bfloat16* wb   = xb + (size_t)3 * CX;

    const int cvt_blocks = (3 * CX + 3 * CW) / (256 * 8);
    convert_kernel<<<dim3(cvt_blocks), 256, 0, stream>>>(q, k, v, Wq, Wk, Wv, xb, wb);
    proj_gemm<<<dim3(MM / 128, EE / 128, 3), 256, 0, stream>>>(
        xb, wb, bq, bk, bv, qws, kws, vtws);
    attn_kernel<<<dim3(SS / 64, BB * HH), 256, 0, stream>>>(
        qws, kws, vtws, mask, out);
}

// Round 13
// 230.571 us; speedup vs baseline: 1.6940x; 1.6940x over previous
//
#include <hip/hip_runtime.h>
#include <hip/hip_bf16.h>

// Problem constants
constexpr int BB = 2;
constexpr int SS = 2048;
constexpr int EE = 1024;
constexpr int HH = 16;
constexpr int DD = 64;
constexpr int MM = BB * SS;              // 4096 rows in the projection GEMMs
constexpr int CX = MM * EE;              // 4194304 elems per X slice (2^22)
constexpr int CW = EE * EE;              // 1048576 elems per W slice (2^20)
// Q pre-scale: 1/sqrt(EMBED_DIM) * log2(e) so attention scores are base-2 logits
#define QSCALE 0.045084220027780106f
#define NEGBIG -1e30f

typedef __attribute__((ext_vector_type(8))) short short8;    // 8 bf16 = 4 VGPRs (MFMA A/B frag)
typedef __attribute__((ext_vector_type(4))) float floatx4;   // MFMA C/D frag

__device__ inline short bf16bits(float x) {
    __hip_bfloat16 h = __float2bfloat16(x);
    return *reinterpret_cast<short*>(&h);
}

__device__ inline unsigned pkbf(float a, float b) {
    return (unsigned)(unsigned short)bf16bits(a) |
           ((unsigned)(unsigned short)bf16bits(b) << 16);
}

__device__ inline float fast_exp2(float x) {
#if __has_builtin(__builtin_amdgcn_exp2f)
    return __builtin_amdgcn_exp2f(x);
#else
    return exp2f(x);
#endif
}

// Async global->LDS, 16 B per lane. LDS dest = wave-uniform base + lane*16.
__device__ inline void gl_lds16(const __hip_bfloat16* g, const short* l) {
    __builtin_amdgcn_global_load_lds(
        (const __attribute__((address_space(1))) void*)g,
        (__attribute__((address_space(3))) void*)l, 16, 0, 0);
}

// ---------------------------------------------------------------------------
// Convert pass: f32 -> bf16, flat over 3 X slices then 3 W slices.
// ---------------------------------------------------------------------------
__global__ __launch_bounds__(256) void convert_kernel(
    const float* __restrict__ x0, const float* __restrict__ x1, const float* __restrict__ x2,
    const float* __restrict__ w0, const float* __restrict__ w1, const float* __restrict__ w2,
    __hip_bfloat16* __restrict__ xb, __hip_bfloat16* __restrict__ wb)
{
    const long long e = (long long)(blockIdx.x * 256 + threadIdx.x) * 8;
    const float* src;
    __hip_bfloat16* dst;
    if (e < 3LL * CX) {
        const int z = (int)(e >> 22);
        const int off = (int)(e & (CX - 1));
        src = ((z == 0) ? x0 : (z == 1) ? x1 : x2) + off;
        dst = xb + e;
    } else {
        const long long e2 = e - 3LL * CX;
        const int z = (int)(e2 >> 20);
        const int off = (int)(e2 & (CW - 1));
        src = ((z == 0) ? w0 : (z == 1) ? w1 : w2) + off;
        dst = wb + e2;
    }
    const float4 a = reinterpret_cast<const float4*>(src)[0];
    const float4 b = reinterpret_cast<const float4*>(src)[1];
    short8 r;
    r[0] = bf16bits(a.x); r[1] = bf16bits(a.y); r[2] = bf16bits(a.z); r[3] = bf16bits(a.w);
    r[4] = bf16bits(b.x); r[5] = bf16bits(b.y); r[6] = bf16bits(b.z); r[7] = bf16bits(b.w);
    *reinterpret_cast<short8*>(dst) = r;
}

// ---------------------------------------------------------------------------
// Projection GEMM (r8 version — best measured): 128x128 tile, BK=32,
// 256 threads, 2-barrier K-loop, async global_load_lds, superrow swizzle
// (granule pos=(r&1)*4+g of row r at slot pos^((r>>1)&7) -> 2-way-free b128
// frag reads with the contiguous DMA dest global_load_lds requires).
// which==0 output (Q) pre-scaled by QSCALE. V stored transposed [B,H,D,S].
// ---------------------------------------------------------------------------
__global__ __launch_bounds__(256) void proj_gemm(
    const __hip_bfloat16* __restrict__ xb,
    const __hip_bfloat16* __restrict__ wb,
    const float* __restrict__ bq, const float* __restrict__ bk, const float* __restrict__ bv,
    __hip_bfloat16* __restrict__ qws,
    __hip_bfloat16* __restrict__ kws,
    __hip_bfloat16* __restrict__ vtws)
{
    const int which = blockIdx.z;
    const __hip_bfloat16* A = xb + (size_t)which * CX;
    const __hip_bfloat16* W = wb + (size_t)which * CW;
    const float* bias = (which == 0) ? bq : (which == 1) ? bk : bv;

    const int m0   = blockIdx.x * 128;
    const int n0   = blockIdx.y * 128;
    const int tid  = threadIdx.x;
    const int wave = tid >> 6;
    const int lane = tid & 63;
    const int l15  = lane & 15;
    const int quad = lane >> 4;
    const int wr   = wave >> 1;
    const int wc   = wave & 1;

    __shared__ __align__(16) short As[128 * 32];   // 8 KiB, superrow-swizzled
    __shared__ __align__(16) short Bs[128 * 32];   // 8 KiB

    const int dpos  = (lane & 7) ^ (lane >> 3);
    const int drloc = 2 * (lane >> 3) + (dpos >> 2);
    const int dgran = (dpos & 3) * 8;              // k-offset in shorts

    const int rbase = (l15 >> 1) * 64;             // superrow offset within tile
    const int rslot = (((l15 & 1) * 4 + quad) ^ (l15 >> 1)) * 8;

    floatx4 acc[4][4] = {};

    for (int k0 = 0; k0 < EE; k0 += 32) {
        __syncthreads();  // WAR: previous iteration's frag reads complete
        #pragma unroll
        for (int p = 0; p < 2; ++p) {
            const int rb16 = wave * 32 + p * 16;   // 16-row issue base
            gl_lds16(A + (size_t)(m0 + rb16 + drloc) * EE + k0 + dgran, &As[rb16 * 32]);
            gl_lds16(W + (size_t)(n0 + rb16 + drloc) * EE + k0 + dgran, &Bs[rb16 * 32]);
        }
        __syncthreads();  // staging visible (drains vmcnt)

        short8 af[4], bf[4];
        #pragma unroll
        for (int mt = 0; mt < 4; ++mt)
            af[mt] = *reinterpret_cast<const short8*>(
                &As[(wr * 32 + mt * 8) * 64 + rbase + rslot]);
        #pragma unroll
        for (int nt = 0; nt < 4; ++nt)
            bf[nt] = *reinterpret_cast<const short8*>(
                &Bs[(wc * 32 + nt * 8) * 64 + rbase + rslot]);

        #pragma unroll
        for (int mt = 0; mt < 4; ++mt)
            #pragma unroll
            for (int nt = 0; nt < 4; ++nt)
                acc[mt][nt] = __builtin_amdgcn_mfma_f32_16x16x32_bf16(af[mt], bf[nt], acc[mt][nt], 0, 0, 0);
    }

    // Epilogue: C/D layout col = lane&15, row = quad*4 + r
    #pragma unroll
    for (int nt = 0; nt < 4; ++nt) {
        const int n = n0 + wc * 64 + nt * 16 + l15;
        const float bval = bias[n];
        const int h = n >> 6, d = n & 63;
        #pragma unroll
        for (int mt = 0; mt < 4; ++mt) {
            #pragma unroll
            for (int r = 0; r < 4; ++r) {
                const int m = m0 + wr * 64 + mt * 16 + quad * 4 + r;
                const int b = m >> 11;
                const int s = m & (SS - 1);
                float val = acc[mt][nt][r] + bval;
                if (which == 0) val *= QSCALE;   // fold softmax scale+log2e into Q
                const __hip_bfloat16 hv = __float2bfloat16(val);
                if (which == 0)
                    qws[(((size_t)b * HH + h) * SS + s) * DD + d] = hv;
                else if (which == 1)
                    kws[(((size_t)b * HH + h) * SS + s) * DD + d] = hv;
                else
                    vtws[(((size_t)b * HH + h) * DD + d) * SS + s] = hv;
            }
        }
    }
}

// ---------------------------------------------------------------------------
// Flash attention (r11 structure) at 32 q-rows / 2 waves per block:
// grid doubles to 2048 blocks -> 7 blocks/CU by LDS (20 KB), ~14 waves/CU
// residency (r11's grid capped at 4 blocks/CU). Per-barrier convoy is 2
// waves instead of 4. K/V staged per 32-q block (DMA traffic x2, L2-fed).
// DMA staging with XOR granule swizzle (slot g^(row&7)); transposed-score +
// no-max softmax; per-wave P transpose through LDS; 2-barrier loop.
// ---------------------------------------------------------------------------
__global__ __launch_bounds__(128) void attn_kernel(
    const __hip_bfloat16* __restrict__ qws,
    const __hip_bfloat16* __restrict__ kws,
    const __hip_bfloat16* __restrict__ vtws,
    const int* __restrict__ amask,
    float* __restrict__ out)
{
    const int bh   = blockIdx.y;
    const int b    = bh >> 4;
    const int q0   = blockIdx.x * 32;
    const int tid  = threadIdx.x;
    const int wave = tid >> 6;       // 0..1
    const int lane = tid & 63;
    const int l15  = lane & 15;
    const int quad = lane >> 4;

    const __hip_bfloat16* Q  = qws  + (size_t)bh * SS * DD;
    const __hip_bfloat16* K  = kws  + (size_t)bh * SS * DD;
    const __hip_bfloat16* VT = vtws + (size_t)bh * DD * SS;
    const int* msk = amask + b * SS;

    __shared__ __align__(16) short Ks[64 * 64];      // [key][d], swizzled (8 KB)
    __shared__ __align__(16) short Vs[64 * 64];      // [d][key], swizzled (8 KB)
    __shared__ __align__(16) short Ps[2][16 * 64];   // per-wave P[q][key] (4 KB)
    short* pw = Ps[wave];

    const int qrow = q0 + wave * 16 + l15;
    const short8 qa0 = *reinterpret_cast<const short8*>(Q + (size_t)qrow * DD + quad * 8);
    const short8 qa1 = *reinterpret_cast<const short8*>(Q + (size_t)qrow * DD + 32 + quad * 8);

    const int swz = l15 & 7;

    // DMA source map (8-row issues): lane covers row rb+(lane>>3),
    // source granule (lane&7)^(lane>>3); dest base+lane*16 realizes
    // slot = g ^ (row&7) for rb a multiple of 8.
    const int srow = lane >> 3;
    const int sg   = ((lane & 7) ^ srow) * 8;

    float l_lane = 0.f;
    floatx4 acc[4] = {};

    for (int kt = 0; kt < SS; kt += 64) {
        __syncthreads();  // WAR: previous tile's LDS reads done

        // stage K [64key x 64d] and V^T [64d x 64key] via DMA (8 issues/wave)
        #pragma unroll
        for (int p = 0; p < 4; ++p) {
            const int rb = wave * 32 + p * 8;
            gl_lds16(K + (size_t)(kt + rb + srow) * DD + sg, &Ks[rb * 64]);
            gl_lds16(VT + (size_t)(rb + srow) * SS + kt + sg, &Vs[rb * 64]);
        }
        __syncthreads();  // staging visible (drains vmcnt)

        floatx4 st[4];
        #pragma unroll
        for (int f = 0; f < 4; ++f) {
            const int krow = (f * 16 + l15) * 64;
            const short8 ka = *reinterpret_cast<const short8*>(&Ks[krow + (quad ^ swz) * 8]);
            const short8 kb = *reinterpret_cast<const short8*>(&Ks[krow + ((quad + 4) ^ swz) * 8]);
            floatx4 z = {};
            z = __builtin_amdgcn_mfma_f32_16x16x32_bf16(ka, qa0, z, 0, 0, 0);
            z = __builtin_amdgcn_mfma_f32_16x16x32_bf16(kb, qa1, z, 0, 0, 0);
            st[f] = z;
        }

        #pragma unroll
        for (int f = 0; f < 4; ++f) {
            const int4 mi = *reinterpret_cast<const int4*>(msk + kt + f * 16 + quad * 4);
            st[f][0] = fast_exp2(st[f][0] + (mi.x ? 0.f : NEGBIG));
            st[f][1] = fast_exp2(st[f][1] + (mi.y ? 0.f : NEGBIG));
            st[f][2] = fast_exp2(st[f][2] + (mi.z ? 0.f : NEGBIG));
            st[f][3] = fast_exp2(st[f][3] + (mi.w ? 0.f : NEGBIG));
            l_lane += st[f][0] + st[f][1] + st[f][2] + st[f][3];
        }

        #pragma unroll
        for (int f = 0; f < 4; ++f) {
            const int slot = (2 * f + (quad >> 1)) ^ swz;
            uint2 pk;
            pk.x = pkbf(st[f][0], st[f][1]);
            pk.y = pkbf(st[f][2], st[f][3]);
            *reinterpret_cast<uint2*>(pw + l15 * 64 + slot * 8 + (quad & 1) * 4) = pk;
        }
        __asm__ volatile("s_waitcnt lgkmcnt(0)" ::: "memory");  // wave-local P drain

        const short8 pa0 = *reinterpret_cast<const short8*>(pw + l15 * 64 + (quad ^ swz) * 8);
        const short8 pa1 = *reinterpret_cast<const short8*>(pw + l15 * 64 + ((quad + 4) ^ swz) * 8);

        #pragma unroll
        for (int nt = 0; nt < 4; ++nt) {
            const int vrow = (nt * 16 + l15) * 64;
            const short8 vb0 = *reinterpret_cast<const short8*>(&Vs[vrow + (quad ^ swz) * 8]);
            const short8 vb1 = *reinterpret_cast<const short8*>(&Vs[vrow + ((quad + 4) ^ swz) * 8]);
            acc[nt] = __builtin_amdgcn_mfma_f32_16x16x32_bf16(pa0, vb0, acc[nt], 0, 0, 0);
            acc[nt] = __builtin_amdgcn_mfma_f32_16x16x32_bf16(pa1, vb1, acc[nt], 0, 0, 0);
        }
    }

    l_lane += __shfl_xor(l_lane, 16, 64);
    l_lane += __shfl_xor(l_lane, 32, 64);
    float lq[4];
    #pragma unroll
    for (int r = 0; r < 4; ++r)
        lq[r] = __shfl(l_lane, quad * 4 + r, 16);

    const size_t obase = (size_t)bh * SS * DD;
    #pragma unroll
    for (int nt = 0; nt < 4; ++nt)
        #pragma unroll
        for (int r = 0; r < 4; ++r) {
            const int qq = q0 + wave * 16 + quad * 4 + r;
            const int d  = nt * 16 + l15;
            out[obase + (size_t)qq * DD + d] = acc[nt][r] / lq[r];
        }
}

extern "C" void kernel_launch(void* const* d_in, const int* in_sizes, int n_in,
                              void* d_out, int out_size, void* d_ws, size_t ws_size,
                              hipStream_t stream) {
    const float* q    = (const float*)d_in[0];
    const float* k    = (const float*)d_in[1];
    const float* v    = (const float*)d_in[2];
    const int*   mask = (const int*)d_in[3];
    const float* Wq   = (const float*)d_in[4];
    const float* bq   = (const float*)d_in[5];
    const float* Wk   = (const float*)d_in[6];
    const float* bk   = (const float*)d_in[7];
    const float* Wv   = (const float*)d_in[8];
    const float* bv   = (const float*)d_in[9];
    float* out = (float*)d_out;

    // Workspace (shorts): qws | kws | vtws | Xbf(3) | Wbf(3)
    __hip_bfloat16* qws  = (__hip_bfloat16*)d_ws;
    __hip_bfloat16* kws  = qws + (size_t)CX;
    __hip_bfloat16* vtws = kws + (size_t)CX;
    __hip_bfloat16* xb   = vtws + (size_t)CX;
    __hip_bfloat16* wb   = xb + (size_t)3 * CX;

    const int cvt_blocks = (3 * CX + 3 * CW) / (256 * 8);
    convert_kernel<<<dim3(cvt_blocks), 256, 0, stream>>>(q, k, v, Wq, Wk, Wv, xb, wb);
    proj_gemm<<<dim3(MM / 128, EE / 128, 3), 256, 0, stream>>>(
        xb, wb, bq, bk, bv, qws, kws, vtws);
    attn_kernel<<<dim3(SS / 32, BB * HH), 128, 0, stream>>>(
        qws, kws, vtws, mask, out);
}

// Round 14
// 213.082 us; speedup vs baseline: 1.8330x; 1.0821x over previous
//
#include <hip/hip_runtime.h>
#include <hip/hip_bf16.h>

// Problem constants
constexpr int BB = 2;
constexpr int SS = 2048;
constexpr int EE = 1024;
constexpr int HH = 16;
constexpr int DD = 64;
constexpr int MM = BB * SS;              // 4096 rows in the projection GEMMs
constexpr int CX = MM * EE;              // 4194304 elems per X slice (2^22)
constexpr int CW = EE * EE;              // 1048576 elems per W slice (2^20)
// Q pre-scale: 1/sqrt(EMBED_DIM) * log2(e) so attention scores are base-2 logits
#define QSCALE 0.045084220027780106f
#define NEGBIG -1e30f

typedef __attribute__((ext_vector_type(8))) short short8;    // 8 bf16 = 4 VGPRs (MFMA A/B frag)
typedef __attribute__((ext_vector_type(4))) float floatx4;   // MFMA C/D frag

__device__ inline short bf16bits(float x) {
    __hip_bfloat16 h = __float2bfloat16(x);
    return *reinterpret_cast<short*>(&h);
}

__device__ inline unsigned pkbf(float a, float b) {
    return (unsigned)(unsigned short)bf16bits(a) |
           ((unsigned)(unsigned short)bf16bits(b) << 16);
}

__device__ inline float fast_exp2(float x) {
#if __has_builtin(__builtin_amdgcn_exp2f)
    return __builtin_amdgcn_exp2f(x);
#else
    return exp2f(x);
#endif
}

// Async global->LDS, 16 B per lane. LDS dest = wave-uniform base + lane*16.
__device__ inline void gl_lds16(const __hip_bfloat16* g, const short* l) {
    __builtin_amdgcn_global_load_lds(
        (const __attribute__((address_space(1))) void*)g,
        (__attribute__((address_space(3))) void*)l, 16, 0, 0);
}

// ---------------------------------------------------------------------------
// Convert pass: f32 -> bf16, flat over 3 X slices then 3 W slices.
// ---------------------------------------------------------------------------
__global__ __launch_bounds__(256) void convert_kernel(
    const float* __restrict__ x0, const float* __restrict__ x1, const float* __restrict__ x2,
    const float* __restrict__ w0, const float* __restrict__ w1, const float* __restrict__ w2,
    __hip_bfloat16* __restrict__ xb, __hip_bfloat16* __restrict__ wb)
{
    const long long e = (long long)(blockIdx.x * 256 + threadIdx.x) * 8;
    const float* src;
    __hip_bfloat16* dst;
    if (e < 3LL * CX) {
        const int z = (int)(e >> 22);
        const int off = (int)(e & (CX - 1));
        src = ((z == 0) ? x0 : (z == 1) ? x1 : x2) + off;
        dst = xb + e;
    } else {
        const long long e2 = e - 3LL * CX;
        const int z = (int)(e2 >> 20);
        const int off = (int)(e2 & (CW - 1));
        src = ((z == 0) ? w0 : (z == 1) ? w1 : w2) + off;
        dst = wb + e2;
    }
    const float4 a = reinterpret_cast<const float4*>(src)[0];
    const float4 b = reinterpret_cast<const float4*>(src)[1];
    short8 r;
    r[0] = bf16bits(a.x); r[1] = bf16bits(a.y); r[2] = bf16bits(a.z); r[3] = bf16bits(a.w);
    r[4] = bf16bits(b.x); r[5] = bf16bits(b.y); r[6] = bf16bits(b.z); r[7] = bf16bits(b.w);
    *reinterpret_cast<short8*>(dst) = r;
}

// ---------------------------------------------------------------------------
// Projection GEMM (r8 version — best measured): 128x128 tile, BK=32,
// 256 threads, 2-barrier K-loop, async global_load_lds, superrow swizzle
// (granule pos=(r&1)*4+g of row r at slot pos^((r>>1)&7) -> 2-way-free b128
// frag reads with the contiguous DMA dest global_load_lds requires).
// which==0 output (Q) pre-scaled by QSCALE. V stored transposed [B,H,D,S].
// ---------------------------------------------------------------------------
__global__ __launch_bounds__(256) void proj_gemm(
    const __hip_bfloat16* __restrict__ xb,
    const __hip_bfloat16* __restrict__ wb,
    const float* __restrict__ bq, const float* __restrict__ bk, const float* __restrict__ bv,
    __hip_bfloat16* __restrict__ qws,
    __hip_bfloat16* __restrict__ kws,
    __hip_bfloat16* __restrict__ vtws)
{
    const int which = blockIdx.z;
    const __hip_bfloat16* A = xb + (size_t)which * CX;
    const __hip_bfloat16* W = wb + (size_t)which * CW;
    const float* bias = (which == 0) ? bq : (which == 1) ? bk : bv;

    const int m0   = blockIdx.x * 128;
    const int n0   = blockIdx.y * 128;
    const int tid  = threadIdx.x;
    const int wave = tid >> 6;
    const int lane = tid & 63;
    const int l15  = lane & 15;
    const int quad = lane >> 4;
    const int wr   = wave >> 1;
    const int wc   = wave & 1;

    __shared__ __align__(16) short As[128 * 32];   // 8 KiB, superrow-swizzled
    __shared__ __align__(16) short Bs[128 * 32];   // 8 KiB

    const int dpos  = (lane & 7) ^ (lane >> 3);
    const int drloc = 2 * (lane >> 3) + (dpos >> 2);
    const int dgran = (dpos & 3) * 8;              // k-offset in shorts

    const int rbase = (l15 >> 1) * 64;             // superrow offset within tile
    const int rslot = (((l15 & 1) * 4 + quad) ^ (l15 >> 1)) * 8;

    floatx4 acc[4][4] = {};

    for (int k0 = 0; k0 < EE; k0 += 32) {
        __syncthreads();  // WAR: previous iteration's frag reads complete
        #pragma unroll
        for (int p = 0; p < 2; ++p) {
            const int rb16 = wave * 32 + p * 16;   // 16-row issue base
            gl_lds16(A + (size_t)(m0 + rb16 + drloc) * EE + k0 + dgran, &As[rb16 * 32]);
            gl_lds16(W + (size_t)(n0 + rb16 + drloc) * EE + k0 + dgran, &Bs[rb16 * 32]);
        }
        __syncthreads();  // staging visible (drains vmcnt)

        short8 af[4], bf[4];
        #pragma unroll
        for (int mt = 0; mt < 4; ++mt)
            af[mt] = *reinterpret_cast<const short8*>(
                &As[(wr * 32 + mt * 8) * 64 + rbase + rslot]);
        #pragma unroll
        for (int nt = 0; nt < 4; ++nt)
            bf[nt] = *reinterpret_cast<const short8*>(
                &Bs[(wc * 32 + nt * 8) * 64 + rbase + rslot]);

        #pragma unroll
        for (int mt = 0; mt < 4; ++mt)
            #pragma unroll
            for (int nt = 0; nt < 4; ++nt)
                acc[mt][nt] = __builtin_amdgcn_mfma_f32_16x16x32_bf16(af[mt], bf[nt], acc[mt][nt], 0, 0, 0);
    }

    // Epilogue: C/D layout col = lane&15, row = quad*4 + r
    #pragma unroll
    for (int nt = 0; nt < 4; ++nt) {
        const int n = n0 + wc * 64 + nt * 16 + l15;
        const float bval = bias[n];
        const int h = n >> 6, d = n & 63;
        #pragma unroll
        for (int mt = 0; mt < 4; ++mt) {
            #pragma unroll
            for (int r = 0; r < 4; ++r) {
                const int m = m0 + wr * 64 + mt * 16 + quad * 4 + r;
                const int b = m >> 11;
                const int s = m & (SS - 1);
                float val = acc[mt][nt][r] + bval;
                if (which == 0) val *= QSCALE;   // fold softmax scale+log2e into Q
                const __hip_bfloat16 hv = __float2bfloat16(val);
                if (which == 0)
                    qws[(((size_t)b * HH + h) * SS + s) * DD + d] = hv;
                else if (which == 1)
                    kws[(((size_t)b * HH + h) * SS + s) * DD + d] = hv;
                else
                    vtws[(((size_t)b * HH + h) * DD + d) * SS + s] = hv;
            }
        }
    }
}

// ---------------------------------------------------------------------------
// Flash attention (r11 structure, best measured) + XCD-aware block swizzle:
// flat block id -> bh = 4*(id&7) + ((id>>3)&3), qtile = id>>5. Assuming
// round-robin XCD = id%8, each XCD's 4 MB L2 then serves only 4 heads
// (~3 MB K/Q/VT working set) instead of all 32 (16 MB) -> DMA fills hit L2,
// shortening the barrier vmcnt drains. Pure index remap; all else = r11:
// DMA staging w/ XOR granule swizzle, transposed-score + no-max softmax,
// per-wave P transpose, 2-barrier loop, 24.6 KB LDS, 64 q-rows / 4 waves.
// ---------------------------------------------------------------------------
__global__ __launch_bounds__(256) void attn_kernel(
    const __hip_bfloat16* __restrict__ qws,
    const __hip_bfloat16* __restrict__ kws,
    const __hip_bfloat16* __restrict__ vtws,
    const int* __restrict__ amask,
    float* __restrict__ out)
{
    const int flatb = blockIdx.y * gridDim.x + blockIdx.x;
    const int bh    = 4 * (flatb & 7) + ((flatb >> 3) & 3);   // XCD-partitioned head
    const int b     = bh >> 4;
    const int q0    = (flatb >> 5) * 64;
    const int tid  = threadIdx.x;
    const int wave = tid >> 6;
    const int lane = tid & 63;
    const int l15  = lane & 15;
    const int quad = lane >> 4;

    const __hip_bfloat16* Q  = qws  + (size_t)bh * SS * DD;
    const __hip_bfloat16* K  = kws  + (size_t)bh * SS * DD;
    const __hip_bfloat16* VT = vtws + (size_t)bh * DD * SS;
    const int* msk = amask + b * SS;

    __shared__ __align__(16) short Ks[64 * 64];      // [key][d], swizzled
    __shared__ __align__(16) short Vs[64 * 64];      // [d][key], swizzled
    __shared__ __align__(16) short Ps[4][16 * 64];   // per-wave P[q][key], swizzled
    short* pw = Ps[wave];

    const int qrow = q0 + wave * 16 + l15;
    const short8 qa0 = *reinterpret_cast<const short8*>(Q + (size_t)qrow * DD + quad * 8);
    const short8 qa1 = *reinterpret_cast<const short8*>(Q + (size_t)qrow * DD + 32 + quad * 8);

    const int swz = l15 & 7;

    // DMA source map (8-row issues): lane covers row rb+(lane>>3),
    // source granule (lane&7)^(lane>>3); dest base+lane*16 realizes
    // slot = g ^ (row&7) for rb a multiple of 8.
    const int srow = lane >> 3;
    const int sg   = ((lane & 7) ^ srow) * 8;

    float l_lane = 0.f;
    floatx4 acc[4] = {};

    for (int kt = 0; kt < SS; kt += 64) {
        __syncthreads();  // WAR: previous tile's LDS reads done

        // stage K [64key x 64d] and V^T [64d x 64key] via DMA (4 issues/wave)
        #pragma unroll
        for (int p = 0; p < 2; ++p) {
            const int rb = wave * 16 + p * 8;
            gl_lds16(K + (size_t)(kt + rb + srow) * DD + sg, &Ks[rb * 64]);
            gl_lds16(VT + (size_t)(rb + srow) * SS + kt + sg, &Vs[rb * 64]);
        }
        __syncthreads();  // staging visible (drains vmcnt)

        floatx4 st[4];
        #pragma unroll
        for (int f = 0; f < 4; ++f) {
            const int krow = (f * 16 + l15) * 64;
            const short8 ka = *reinterpret_cast<const short8*>(&Ks[krow + (quad ^ swz) * 8]);
            const short8 kb = *reinterpret_cast<const short8*>(&Ks[krow + ((quad + 4) ^ swz) * 8]);
            floatx4 z = {};
            z = __builtin_amdgcn_mfma_f32_16x16x32_bf16(ka, qa0, z, 0, 0, 0);
            z = __builtin_amdgcn_mfma_f32_16x16x32_bf16(kb, qa1, z, 0, 0, 0);
            st[f] = z;
        }

        #pragma unroll
        for (int f = 0; f < 4; ++f) {
            const int4 mi = *reinterpret_cast<const int4*>(msk + kt + f * 16 + quad * 4);
            st[f][0] = fast_exp2(st[f][0] + (mi.x ? 0.f : NEGBIG));
            st[f][1] = fast_exp2(st[f][1] + (mi.y ? 0.f : NEGBIG));
            st[f][2] = fast_exp2(st[f][2] + (mi.z ? 0.f : NEGBIG));
            st[f][3] = fast_exp2(st[f][3] + (mi.w ? 0.f : NEGBIG));
            l_lane += st[f][0] + st[f][1] + st[f][2] + st[f][3];
        }

        #pragma unroll
        for (int f = 0; f < 4; ++f) {
            const int slot = (2 * f + (quad >> 1)) ^ swz;
            uint2 pk;
            pk.x = pkbf(st[f][0], st[f][1]);
            pk.y = pkbf(st[f][2], st[f][3]);
            *reinterpret_cast<uint2*>(pw + l15 * 64 + slot * 8 + (quad & 1) * 4) = pk;
        }
        __asm__ volatile("s_waitcnt lgkmcnt(0)" ::: "memory");  // wave-local P drain

        const short8 pa0 = *reinterpret_cast<const short8*>(pw + l15 * 64 + (quad ^ swz) * 8);
        const short8 pa1 = *reinterpret_cast<const short8*>(pw + l15 * 64 + ((quad + 4) ^ swz) * 8);

        #pragma unroll
        for (int nt = 0; nt < 4; ++nt) {
            const int vrow = (nt * 16 + l15) * 64;
            const short8 vb0 = *reinterpret_cast<const short8*>(&Vs[vrow + (quad ^ swz) * 8]);
            const short8 vb1 = *reinterpret_cast<const short8*>(&Vs[vrow + ((quad + 4) ^ swz) * 8]);
            acc[nt] = __builtin_amdgcn_mfma_f32_16x16x32_bf16(pa0, vb0, acc[nt], 0, 0, 0);
            acc[nt] = __builtin_amdgcn_mfma_f32_16x16x32_bf16(pa1, vb1, acc[nt], 0, 0, 0);
        }
    }

    l_lane += __shfl_xor(l_lane, 16, 64);
    l_lane += __shfl_xor(l_lane, 32, 64);
    float lq[4];
    #pragma unroll
    for (int r = 0; r < 4; ++r)
        lq[r] = __shfl(l_lane, quad * 4 + r, 16);

    const size_t obase = (size_t)bh * SS * DD;
    #pragma unroll
    for (int nt = 0; nt < 4; ++nt)
        #pragma unroll
        for (int r = 0; r < 4; ++r) {
            const int qq = q0 + wave * 16 + quad * 4 + r;
            const int d  = nt * 16 + l15;
            out[obase + (size_t)qq * DD + d] = acc[nt][r] / lq[r];
        }
}

extern "C" void kernel_launch(void* const* d_in, const int* in_sizes, int n_in,
                              void* d_out, int out_size, void* d_ws, size_t ws_size,
                              hipStream_t stream) {
    const float* q    = (const float*)d_in[0];
    const float* k    = (const float*)d_in[1];
    const float* v    = (const float*)d_in[2];
    const int*   mask = (const int*)d_in[3];
    const float* Wq   = (const float*)d_in[4];
    const float* bq   = (const float*)d_in[5];
    const float* Wk   = (const float*)d_in[6];
    const float* bk   = (const float*)d_in[7];
    const float* Wv   = (const float*)d_in[8];
    const float* bv   = (const float*)d_in[9];
    float* out = (float*)d_out;

    // Workspace (shorts): qws | kws | vtws | Xbf(3) | Wbf(3)
    __hip_bfloat16* qws  = (__hip_bfloat16*)d_ws;
    __hip_bfloat16* kws  = qws + (size_t)CX;
    __hip_bfloat16* vtws = kws + (size_t)CX;
    __hip_bfloat16* xb   = vtws + (size_t)CX;
    __hip_bfloat16* wb   = xb + (size_t)3 * CX;

    const int cvt_blocks = (3 * CX + 3 * CW) / (256 * 8);
    convert_kernel<<<dim3(cvt_blocks), 256, 0, stream>>>(q, k, v, Wq, Wk, Wv, xb, wb);
    proj_gemm<<<dim3(MM / 128, EE / 128, 3), 256, 0, stream>>>(
        xb, wb, bq, bk, bv, qws, kws, vtws);
    attn_kernel<<<dim3(SS / 64, BB * HH), 256, 0, stream>>>(
        qws, kws, vtws, mask, out);
}